// Round 1
// baseline (506.911 us; speedup 1.0000x reference)
//
#include <hip/hip_runtime.h>
#include <cmath>

#define NN 4096
#define KK 32
#define DD 256
#define HH 128
#define G3 384   // 3*H

// ---------------------------------------------------------------------------
// Kernel 1: per-cluster ordered sentence lists + lengths; block KK computes
// the weight-norm scale g/||v||.
// ---------------------------------------------------------------------------
__global__ void build_order_k(const int* __restrict__ labels,
                              const float* __restrict__ lin_v,
                              const float* __restrict__ lin_g,
                              int* __restrict__ order,
                              int* __restrict__ len,
                              float* __restrict__ scale) {
  const int c = blockIdx.x;
  const int lane = threadIdx.x;
  if (c < KK) {
    int count = 0;
    for (int base = 0; base < NN; base += 64) {
      const int i = base + lane;
      const bool f = (labels[i] == c);
      const unsigned long long m = __ballot(f);
      const unsigned long long below = m & ((1ull << lane) - 1ull);
      if (f) order[c * NN + count + __popcll(below)] = i;
      count += __popcll(m);
    }
    if (lane == 0) len[c] = count;
  } else {
    float s = 0.f;
    for (int j = lane; j < G3; j += 64) { const float v = lin_v[j]; s += v * v; }
    for (int off = 32; off; off >>= 1) s += __shfl_down(s, off);
    if (lane == 0) scale[0] = lin_g[0] / sqrtf(s);
  }
}

// ---------------------------------------------------------------------------
// Kernel 2/4: out[i][g] = bias[g] + sum_d X[i][d] * W[g][d]
// Tiled SGEMM: 64 rows x 64 gates per block, 256 threads, 4x4 micro-tile.
// ---------------------------------------------------------------------------
template<int DIN>
__global__ __launch_bounds__(256) void gemm_ih_k(const float* __restrict__ X,
                                                 const float* __restrict__ W,
                                                 const float* __restrict__ bias,
                                                 float* __restrict__ out, int M) {
  __shared__ float Xs[16][65];
  __shared__ float Ws[16][65];
  const int i0 = blockIdx.x * 64;
  const int g0 = blockIdx.y * 64;
  const int t  = threadIdx.x;
  const int it = t & 15;
  const int gt = t >> 4;
  float acc[4][4] = {};
  for (int k0 = 0; k0 < DIN; k0 += 16) {
#pragma unroll
    for (int l = 0; l < 4; ++l) {
      const int idx = t + l * 256;
      const int r = idx >> 4;
      const int cc = idx & 15;
      const int gi = i0 + r;
      Xs[cc][r] = (gi < M) ? X[(size_t)gi * DIN + k0 + cc] : 0.f;
      Ws[cc][r] = W[(size_t)(g0 + r) * DIN + k0 + cc];
    }
    __syncthreads();
#pragma unroll
    for (int k = 0; k < 16; ++k) {
      float a[4], b[4];
#pragma unroll
      for (int x = 0; x < 4; ++x) a[x] = Xs[k][it * 4 + x];
#pragma unroll
      for (int y = 0; y < 4; ++y) b[y] = Ws[k][gt * 4 + y];
#pragma unroll
      for (int x = 0; x < 4; ++x)
#pragma unroll
        for (int y = 0; y < 4; ++y)
          acc[x][y] += a[x] * b[y];
    }
    __syncthreads();
  }
#pragma unroll
  for (int x = 0; x < 4; ++x) {
    const int gi = i0 + it * 4 + x;
    if (gi >= M) continue;
#pragma unroll
    for (int y = 0; y < 4; ++y) {
      const int gg = g0 + gt * 4 + y;
      out[(size_t)gi * G3 + gg] = acc[x][y] + bias[gg];
    }
  }
}

// ---------------------------------------------------------------------------
// Kernel 3/5: GRU recurrence, one block per cluster, 384 threads.
// Thread t owns W_hh row t (128 floats in VGPRs). h lives in LDS (broadcast
// reads). xw loads for the current step are issued before the matvec so their
// L2 latency hides under the FMA chain.
// ---------------------------------------------------------------------------
__global__ __launch_bounds__(384) void gru_rec_k(
    const float* __restrict__ xw,      // [(NN+KK)][384]
    const float* __restrict__ W_hh,    // [384][128]
    const float* __restrict__ b_hh,    // [384]
    const float* __restrict__ b_ih,    // [384] fallback (empty cluster, layer0)
    const int* __restrict__ order,
    const int* __restrict__ len,
    float* __restrict__ h_seq,         // [(NN+KK)][128] or nullptr
    float* __restrict__ h_final,       // [KK][128] or nullptr
    int use_slot_xw)                   // 0: layer0, 1: layer1
{
  const int c = blockIdx.x;
  const int t = threadIdx.x;
  float4 w[32];
  {
    const float4* Wr = (const float4*)(W_hh + (size_t)t * HH);
#pragma unroll
    for (int q = 0; q < 32; ++q) w[q] = Wr[q];
  }
  const float bb = b_hh[t];
  __shared__ __align__(16) float h[HH];
  __shared__ float hw[G3];
  if (t < HH) h[t] = 0.f;
  const int L = len[c];
  const int Lr = (L > 0) ? L : 1;
  __syncthreads();
  for (int step = 0; step < Lr; ++step) {
    // --- prefetch this step's xw (threads 0..127) -------------------------
    float xr = 0.f, xz = 0.f, xn = 0.f;
    int slot = NN + c;
    if (t < HH) {
      const int sent = (step < L) ? order[c * NN + step] : -1;
      if (sent >= 0) slot = sent;
      if (use_slot_xw || sent >= 0) {
        const float* xrow = xw + (size_t)slot * G3;
        xr = xrow[t]; xz = xrow[HH + t]; xn = xrow[2 * HH + t];
      } else {
        xr = b_ih[t]; xz = b_ih[HH + t]; xn = b_ih[2 * HH + t];
      }
    }
    // --- hw[t] = b_hh[t] + W_hh[t,:] . h ---------------------------------
    float acc = bb;
    const float4* hv = (const float4*)h;
#pragma unroll
    for (int q = 0; q < 32; ++q) {
      const float4 hq = hv[q];
      acc += w[q].x * hq.x + w[q].y * hq.y + w[q].z * hq.z + w[q].w * hq.w;
    }
    hw[t] = acc;
    __syncthreads();
    // --- gates (threads 0..127) ------------------------------------------
    if (t < HH) {
      const float r = 1.f / (1.f + expf(-(xr + hw[t])));
      const float z = 1.f / (1.f + expf(-(xz + hw[HH + t])));
      const float n = tanhf(xn + r * hw[2 * HH + t]);
      const float hnew = (1.f - z) * n + z * h[t];
      h[t] = hnew;
      if (h_seq) h_seq[(size_t)slot * HH + t] = hnew;
      if (h_final && step == Lr - 1) h_final[(size_t)c * HH + t] = hnew;
    }
    __syncthreads();
  }
}

// ---------------------------------------------------------------------------
// Kernel 6: one wave per sentence -> scores[i] = tanh(scale * dot + b)
// ---------------------------------------------------------------------------
__global__ __launch_bounds__(256) void score_k(const float* __restrict__ sent,
                                               const int* __restrict__ labels,
                                               const float* __restrict__ ce,
                                               const float* __restrict__ lin_v,
                                               const float* __restrict__ scale,
                                               const float* __restrict__ lin_b,
                                               float* __restrict__ scores) {
  const int wid = threadIdx.x >> 6;
  const int lane = threadIdx.x & 63;
  const int i = blockIdx.x * 4 + wid;
  const float4* s4 = (const float4*)(sent + (size_t)i * DD);
  const float4* v4 = (const float4*)lin_v;
  const float4 a = s4[lane];
  const float4 b = v4[lane];
  float acc = a.x * b.x + a.y * b.y + a.z * b.z + a.w * b.w;
  if (lane < 32) {
    const float4* c4 = (const float4*)(ce + (size_t)labels[i] * HH);
    const float4 hh = c4[lane];
    const float4 vb = v4[64 + lane];
    acc += hh.x * vb.x + hh.y * vb.y + hh.z * vb.z + hh.w * vb.w;
  }
  for (int off = 32; off; off >>= 1) acc += __shfl_down(acc, off);
  if (lane == 0) scores[i] = tanhf(scale[0] * acc + lin_b[0]);
}

// ---------------------------------------------------------------------------
// Kernel 7: per-cluster score sums via order lists (one wave per cluster)
// ---------------------------------------------------------------------------
__global__ void clu_k(const float* __restrict__ scores,
                      const int* __restrict__ order,
                      const int* __restrict__ len,
                      float* __restrict__ clu) {
  const int c = blockIdx.x;
  const int lane = threadIdx.x;
  const int L = len[c];
  float acc = 0.f;
  for (int p = lane; p < L; p += 64) acc += scores[order[c * NN + p]];
  for (int off = 32; off; off >>= 1) acc += __shfl_down(acc, off);
  if (lane == 0) clu[c] = acc;
}

// ---------------------------------------------------------------------------
// Kernel 8: final blend with position scores
// ---------------------------------------------------------------------------
__global__ void final_k(const float* __restrict__ scores,
                        const int* __restrict__ labels,
                        const float* __restrict__ clu,
                        float* __restrict__ out) {
  const int i = blockIdx.x * blockDim.x + threadIdx.x;
  if (i >= NN) return;
  float ps = expf(-(float)(i + 1) * 0.0625f);   // 1/4096^(1/3) == 1/16
  ps = fmaxf(0.5f, ps);
  out[i] = 0.5f * (scores[i] / clu[labels[i]]) + 0.5f * ps;
}

// ---------------------------------------------------------------------------
extern "C" void kernel_launch(void* const* d_in, const int* in_sizes, int n_in,
                              void* d_out, int out_size, void* d_ws, size_t ws_size,
                              hipStream_t stream) {
  const float* sent   = (const float*)d_in[0];
  const int*   labels = (const int*)d_in[1];
  const float* W_ih0  = (const float*)d_in[2];
  const float* W_hh0  = (const float*)d_in[3];
  const float* b_ih0  = (const float*)d_in[4];
  const float* b_hh0  = (const float*)d_in[5];
  const float* W_ih1  = (const float*)d_in[6];
  const float* W_hh1  = (const float*)d_in[7];
  const float* b_ih1  = (const float*)d_in[8];
  const float* b_hh1  = (const float*)d_in[9];
  const float* lin_v  = (const float*)d_in[10];
  const float* lin_g  = (const float*)d_in[11];
  const float* lin_b  = (const float*)d_in[12];
  float* out = (float*)d_out;

  char* ws = (char*)d_ws;
  size_t off = 0;
  auto alloc = [&](size_t bytes) -> void* {
    void* p = ws + off;
    off = (off + bytes + 255) & ~(size_t)255;
    return p;
  };
  int*   order  = (int*)  alloc((size_t)KK * NN * sizeof(int));
  int*   len    = (int*)  alloc(KK * sizeof(int));
  float* scale  = (float*)alloc(sizeof(float));
  float* xw     = (float*)alloc((size_t)(NN + KK) * G3 * sizeof(float));
  float* h1     = (float*)alloc((size_t)(NN + KK) * HH * sizeof(float));
  float* ce     = (float*)alloc((size_t)KK * HH * sizeof(float));
  float* scores = (float*)alloc(NN * sizeof(float));
  float* clu    = (float*)alloc(KK * sizeof(float));
  (void)ws_size; (void)in_sizes; (void)n_in; (void)out_size;

  build_order_k<<<dim3(KK + 1), dim3(64), 0, stream>>>(labels, lin_v, lin_g,
                                                       order, len, scale);
  gemm_ih_k<DD><<<dim3(64, 6), dim3(256), 0, stream>>>(sent, W_ih0, b_ih0, xw, NN);
  gru_rec_k<<<dim3(KK), dim3(G3), 0, stream>>>(xw, W_hh0, b_hh0, b_ih0,
                                               order, len, h1, (float*)nullptr, 0);
  gemm_ih_k<HH><<<dim3(65, 6), dim3(256), 0, stream>>>(h1, W_ih1, b_ih1, xw, NN + KK);
  gru_rec_k<<<dim3(KK), dim3(G3), 0, stream>>>(xw, W_hh1, b_hh1, b_ih1,
                                               order, len, (float*)nullptr, ce, 1);
  score_k<<<dim3(NN / 4), dim3(256), 0, stream>>>(sent, labels, ce, lin_v,
                                                  scale, lin_b, scores);
  clu_k<<<dim3(KK), dim3(64), 0, stream>>>(scores, order, len, clu);
  final_k<<<dim3(16), dim3(256), 0, stream>>>(scores, labels, clu, out);
}